// Round 4
// baseline (113.060 us; speedup 1.0000x reference)
//
#include <hip/hip_runtime.h>
#include <hip/hip_fp16.h>
#include <math.h>

#define BATCH    64
#define IN_CAPS  2048
#define IN_DIM   16
#define NUM_CAPS 32
#define DIM_CAPS 16
#define NROUTE   3
#define CAPS_EPS 1e-7f

typedef unsigned short ushort_t;

// ---------------------------------------------------------------------------
// Kernel A: hat[b][j][i][m] = sum_n W[i][j][n][m] * x[b][i][n]   (fp16 out)
// grid 1024 = 128 i-groups x 8 j-groups; 256 threads = 4 waves (wave -> j).
// Lane holds W[i,j,:,m0:m0+4] in 16 float4 regs. NO LDS, NO barriers:
// each lane streams all 64 batches, loading its x row (64B) directly from
// global (quad-redundant; coalescer merges), double-buffered in registers.
// ---------------------------------------------------------------------------
__global__ __launch_bounds__(256) void caps_hat_kernel(
    const float* __restrict__ x, const float* __restrict__ W,
    ushort_t* __restrict__ hat)
{
  const int bid   = blockIdx.x;
  const int ig    = bid & 127;     // i-group of 16
  const int jb    = bid >> 7;      // 0..7
  const int t     = threadIdx.x;
  const int wv    = t >> 6;        // wave 0..3
  const int l     = t & 63;
  const int j     = jb * 4 + wv;
  const int i_loc = l >> 2;
  const int m0    = (l & 3) * 4;
  const int i     = ig * 16 + i_loc;

  float4 Wr[16];
  {
    const float* wbase = W + (((size_t)i * NUM_CAPS + j) * IN_DIM) * DIM_CAPS + m0;
#pragma unroll
    for (int n = 0; n < 16; ++n)
      Wr[n] = *reinterpret_cast<const float4*>(wbase + n * DIM_CAPS);
  }

  const float* xrow = x + (size_t)i * IN_DIM;          // + b*IN_CAPS*IN_DIM
  ushort_t* hbase = hat + (((size_t)j * IN_CAPS + i) * DIM_CAPS + m0);

  float4 xb[4], xn[4];
#pragma unroll
  for (int k = 0; k < 4; ++k)
    xb[k] = *reinterpret_cast<const float4*>(xrow + 4 * k);

  for (int b = 0; b < BATCH; ++b) {
    if (b + 1 < BATCH) {
      const float* xr = xrow + (size_t)(b + 1) * (IN_CAPS * IN_DIM);
#pragma unroll
      for (int k = 0; k < 4; ++k)
        xn[k] = *reinterpret_cast<const float4*>(xr + 4 * k);
    }
    float4 acc = make_float4(0.f, 0.f, 0.f, 0.f);
#pragma unroll
    for (int nb = 0; nb < 4; ++nb) {
      const float4 xv = xb[nb];
      acc.x = fmaf(Wr[4 * nb + 0].x, xv.x, acc.x);
      acc.y = fmaf(Wr[4 * nb + 0].y, xv.x, acc.y);
      acc.z = fmaf(Wr[4 * nb + 0].z, xv.x, acc.z);
      acc.w = fmaf(Wr[4 * nb + 0].w, xv.x, acc.w);
      acc.x = fmaf(Wr[4 * nb + 1].x, xv.y, acc.x);
      acc.y = fmaf(Wr[4 * nb + 1].y, xv.y, acc.y);
      acc.z = fmaf(Wr[4 * nb + 1].z, xv.y, acc.z);
      acc.w = fmaf(Wr[4 * nb + 1].w, xv.y, acc.w);
      acc.x = fmaf(Wr[4 * nb + 2].x, xv.z, acc.x);
      acc.y = fmaf(Wr[4 * nb + 2].y, xv.z, acc.y);
      acc.z = fmaf(Wr[4 * nb + 2].z, xv.z, acc.z);
      acc.w = fmaf(Wr[4 * nb + 2].w, xv.z, acc.w);
      acc.x = fmaf(Wr[4 * nb + 3].x, xv.w, acc.x);
      acc.y = fmaf(Wr[4 * nb + 3].y, xv.w, acc.y);
      acc.z = fmaf(Wr[4 * nb + 3].z, xv.w, acc.z);
      acc.w = fmaf(Wr[4 * nb + 3].w, xv.w, acc.w);
    }
    ushort4 st;
    st.x = __half_as_ushort(__float2half(acc.x));
    st.y = __half_as_ushort(__float2half(acc.y));
    st.z = __half_as_ushort(__float2half(acc.z));
    st.w = __half_as_ushort(__float2half(acc.w));
    *reinterpret_cast<ushort4*>(hbase + (size_t)b * (NUM_CAPS * IN_CAPS * DIM_CAPS)) = st;
#pragma unroll
    for (int k = 0; k < 4; ++k) xb[k] = xn[k];
  }
}

// ---------------------------------------------------------------------------
// Kernel B: 3-iteration routing for one (b,j). hat slice held in REGISTERS:
// 512 threads; chunk u = t + 512q (16B, coalesced). Pair (t, t^1) shares the
// 8 capsules i = (t>>1) + 256q; even lane holds m 0..7, odd lane m 8..15.
// Block reduction: split-butterfly (9 shfl for 8 values), m = f(lane bits).
// ---------------------------------------------------------------------------
__global__ __launch_bounds__(512) void caps_route_kernel(
    const ushort_t* __restrict__ hat, float* __restrict__ out)
{
  __shared__ float red[8][20];   // [wave][m(16) + E(1) + pad]
  __shared__ float outs[16];

  const int bid  = blockIdx.x;            // = b*32 + j
  const int t    = threadIdx.x;
  const int lane = t & 63;
  const int wv   = t >> 6;
  const int mh   = t & 1;                 // m-half: 0 -> m 0..7, 1 -> m 8..15

  const ushort_t* base = hat + (size_t)bid * (IN_CAPS * DIM_CAPS);

  uint4 g[8];
#pragma unroll
  for (int q = 0; q < 8; ++q)
    g[q] = *reinterpret_cast<const uint4*>(base + (size_t)(t + 512 * q) * 8);

  // H(q,s): fp16 value of hat[i_q][8*mh + s]
#define HVAL(q, s) __half2float(__ushort_as_half((ushort_t)( \
    ((s) & 1) ? (((const unsigned int*)&g[(q)])[(s) >> 1] >> 16) \
              : (((const unsigned int*)&g[(q)])[(s) >> 1] & 0xffffu))))

  const int b1 = (lane >> 1) & 1;
  const int b2 = (lane >> 2) & 1;
  const int b3 = (lane >> 3) & 1;
  // final m index this lane's butterfly result represents
  const int m_fin = 8 * mh + 4 * b3 + 2 * b2 + b1;

  float lg[8];
#pragma unroll
  for (int q = 0; q < 8; ++q) lg[q] = 0.f;

  for (int r = 0; r < NROUTE; ++r) {
    float e[8];
    float Ep = 0.f;
    if (r == 0) {
#pragma unroll
      for (int q = 0; q < 8; ++q) e[q] = 1.f;
    } else {
#pragma unroll
      for (int q = 0; q < 8; ++q) { e[q] = __expf(lg[q]); Ep += e[q]; }
    }

    // acc[s] = sum over my 8 i's of e_i * hat[i][8*mh+s]
    float acc[8];
#pragma unroll
    for (int s = 0; s < 8; ++s) {
      float a = 0.f;
#pragma unroll
      for (int q = 0; q < 8; ++q) a = fmaf(e[q], HVAL(q, s), a);
      acc[s] = a;
    }

    // ---- split-butterfly reduction over the wave (m-half already on bit0)
    float v4[4];
#pragma unroll
    for (int k = 0; k < 4; ++k) {               // xor 2  <-> s bit0
      float send = b1 ? acc[2 * k] : acc[2 * k + 1];
      float recv = __shfl_xor(send, 2);
      float keep = b1 ? acc[2 * k + 1] : acc[2 * k];
      v4[k] = keep + recv;                      // s = 2k + b1
    }
    float v2[2];
#pragma unroll
    for (int k = 0; k < 2; ++k) {               // xor 4  <-> s bit1
      float send = b2 ? v4[2 * k] : v4[2 * k + 1];
      float recv = __shfl_xor(send, 4);
      float keep = b2 ? v4[2 * k + 1] : v4[2 * k];
      v2[k] = keep + recv;                      // s = 4k + 2*b2 + b1
    }
    float z;
    {                                           // xor 8  <-> s bit2
      float send = b3 ? v2[0] : v2[1];
      float recv = __shfl_xor(send, 8);
      float keep = b3 ? v2[1] : v2[0];
      z = keep + recv;                          // s = 4*b3 + 2*b2 + b1
    }
    z += __shfl_xor(z, 16);
    z += __shfl_xor(z, 32);                     // summed over whole wave

    if (r > 0) {                                // E over wave: bits 1..5 only
      Ep += __shfl_xor(Ep, 2);
      Ep += __shfl_xor(Ep, 4);
      Ep += __shfl_xor(Ep, 8);
      Ep += __shfl_xor(Ep, 16);
      Ep += __shfl_xor(Ep, 32);
      if (lane == 16) red[wv][16] = Ep;
    }
    if (lane < 16) red[wv][m_fin] = z;
    __syncthreads();

    if (t < 16) {
      float s = 0.f;
#pragma unroll
      for (int w = 0; w < 8; ++w) s += red[w][t];
      float E;
      if (r == 0) E = (float)IN_CAPS;
      else {
        E = 0.f;
#pragma unroll
        for (int w = 0; w < 8; ++w) E += red[w][16];
      }
      float sm = s / E;
      float n2 = sm * sm;
#pragma unroll
      for (int off = 8; off >= 1; off >>= 1) n2 += __shfl_xor(n2, off);
      const float scale = n2 / (1.0f + n2) * rsqrtf(n2 + CAPS_EPS);
      const float o = scale * sm;
      outs[t] = o;
      if (r == NROUTE - 1)
        out[(size_t)bid * DIM_CAPS + t] = o;
    }
    __syncthreads();

    if (r < NROUTE - 1) {
      // logit update: lg_i += sum_m outs[m]*hat[i][m]; my half + partner half
#pragma unroll
      for (int q = 0; q < 8; ++q) {
        float d = 0.f;
#pragma unroll
        for (int s = 0; s < 8; ++s) d = fmaf(outs[8 * mh + s], HVAL(q, s), d);
        d += __shfl_xor(d, 1);                  // add partner's m-half
        lg[q] += d;
      }
    }
  }
#undef HVAL
}

extern "C" void kernel_launch(void* const* d_in, const int* in_sizes, int n_in,
                              void* d_out, int out_size, void* d_ws, size_t ws_size,
                              hipStream_t stream) {
  (void)in_sizes; (void)n_in; (void)out_size; (void)ws_size;
  const float* x = (const float*)d_in[0];      // [64][2048][16]
  const float* W = (const float*)d_in[1];      // [2048][32][16][16]
  float* outp = (float*)d_out;                 // [64][32][16]
  ushort_t* hat = (ushort_t*)d_ws;             // [64][32][2048][16] fp16 = 134 MB

  caps_hat_kernel<<<dim3(1024), dim3(256), 0, stream>>>(x, W, hat);
  caps_route_kernel<<<dim3(BATCH * NUM_CAPS), dim3(512), 0, stream>>>(hat, outp);
}

// Round 5
// 86.295 us; speedup vs baseline: 1.3102x; 1.3102x over previous
//
#include <hip/hip_runtime.h>
#include <hip/hip_fp16.h>
#include <math.h>

#define BATCH    64
#define IN_CAPS  2048
#define IN_DIM   16
#define NUM_CAPS 32
#define DIM_CAPS 16
#define NROUTE   3
#define CAPS_EPS 1e-7f

typedef unsigned short ushort_t;

// ---------------------------------------------------------------------------
// Kernel A: hat[b][j][i][m] = sum_n W[i][j][n][m] * x[b][i][n]   (fp16 out)
// grid (128, 32) = (i-group, j); 256 threads = 4 waves; wave wv owns the 16
// batches [16*wv, 16*wv+16). No LDS, no barriers. Lane holds W[i,j,:,m0+0..3]
// in 16 float4 regs (W read exactly once HBM-wide). x rows (64B) loaded
// directly, quad-redundant (wave reads 1KB contiguous; L2 absorbs overlap).
// Unconditional wrap-around prefetch -> compiler can software-pipeline.
// ---------------------------------------------------------------------------
__global__ __launch_bounds__(256) void caps_hat_kernel(
    const float* __restrict__ x, const float* __restrict__ W,
    ushort_t* __restrict__ hat)
{
  const int ig    = blockIdx.x;    // 0..127
  const int j     = blockIdx.y;    // 0..31
  const int t     = threadIdx.x;
  const int wv    = t >> 6;        // wave 0..3 -> b-quarter
  const int l     = t & 63;
  const int i_loc = l >> 2;
  const int m0    = (l & 3) * 4;
  const int i     = ig * 16 + i_loc;

  float4 Wr[16];
  {
    const float* wbase = W + (((size_t)i * NUM_CAPS + j) * IN_DIM) * DIM_CAPS + m0;
#pragma unroll
    for (int n = 0; n < 16; ++n)
      Wr[n] = *reinterpret_cast<const float4*>(wbase + n * DIM_CAPS);
  }

  const int b0 = wv * 16;
  const float* xrow = x + ((size_t)b0 * IN_CAPS + i) * IN_DIM;
  ushort_t* hbase =
      hat + ((((size_t)b0 * NUM_CAPS) + j) * IN_CAPS + i) * DIM_CAPS + m0;

  const size_t xstride = (size_t)IN_CAPS * IN_DIM;               // per b
  const size_t hstride = (size_t)NUM_CAPS * IN_CAPS * DIM_CAPS;  // per b

  float4 xb[4], xn[4];
#pragma unroll
  for (int k = 0; k < 4; ++k)
    xb[k] = *reinterpret_cast<const float4*>(xrow + 4 * k);

#pragma unroll
  for (int bi = 0; bi < 16; ++bi) {
    const int nbi = (bi + 1) & 15;   // wrap: always-valid unconditional prefetch
    const float* xr = xrow + (size_t)nbi * xstride;
#pragma unroll
    for (int k = 0; k < 4; ++k)
      xn[k] = *reinterpret_cast<const float4*>(xr + 4 * k);

    float4 acc = make_float4(0.f, 0.f, 0.f, 0.f);
#pragma unroll
    for (int nb = 0; nb < 4; ++nb) {
      const float4 xv = xb[nb];
      acc.x = fmaf(Wr[4 * nb + 0].x, xv.x, acc.x);
      acc.y = fmaf(Wr[4 * nb + 0].y, xv.x, acc.y);
      acc.z = fmaf(Wr[4 * nb + 0].z, xv.x, acc.z);
      acc.w = fmaf(Wr[4 * nb + 0].w, xv.x, acc.w);
      acc.x = fmaf(Wr[4 * nb + 1].x, xv.y, acc.x);
      acc.y = fmaf(Wr[4 * nb + 1].y, xv.y, acc.y);
      acc.z = fmaf(Wr[4 * nb + 1].z, xv.y, acc.z);
      acc.w = fmaf(Wr[4 * nb + 1].w, xv.y, acc.w);
      acc.x = fmaf(Wr[4 * nb + 2].x, xv.z, acc.x);
      acc.y = fmaf(Wr[4 * nb + 2].y, xv.z, acc.y);
      acc.z = fmaf(Wr[4 * nb + 2].z, xv.z, acc.z);
      acc.w = fmaf(Wr[4 * nb + 2].w, xv.z, acc.w);
      acc.x = fmaf(Wr[4 * nb + 3].x, xv.w, acc.x);
      acc.y = fmaf(Wr[4 * nb + 3].y, xv.w, acc.y);
      acc.z = fmaf(Wr[4 * nb + 3].z, xv.w, acc.z);
      acc.w = fmaf(Wr[4 * nb + 3].w, xv.w, acc.w);
    }
    ushort4 st;
    st.x = __half_as_ushort(__float2half(acc.x));
    st.y = __half_as_ushort(__float2half(acc.y));
    st.z = __half_as_ushort(__float2half(acc.z));
    st.w = __half_as_ushort(__float2half(acc.w));
    *reinterpret_cast<ushort4*>(hbase + (size_t)bi * hstride) = st;

#pragma unroll
    for (int k = 0; k < 4; ++k) xb[k] = xn[k];
  }
}

// ---------------------------------------------------------------------------
// Kernel B: 3-iteration routing for one (b,j). hat slice held in REGISTERS:
// 512 threads; chunk u = t + 512q (16B, coalesced). Pair (t, t^1) shares the
// 8 capsules i = (t>>1) + 256q; even lane holds m 0..7, odd lane m 8..15.
// Block reduction: split-butterfly (9 shfl for 8 values), m = f(lane bits).
// ---------------------------------------------------------------------------
__global__ __launch_bounds__(512) void caps_route_kernel(
    const ushort_t* __restrict__ hat, float* __restrict__ out)
{
  __shared__ float red[8][20];   // [wave][m(16) + E(1) + pad]
  __shared__ float outs[16];

  const int bid  = blockIdx.x;            // = b*32 + j
  const int t    = threadIdx.x;
  const int lane = t & 63;
  const int wv   = t >> 6;
  const int mh   = t & 1;                 // m-half: 0 -> m 0..7, 1 -> m 8..15

  const ushort_t* base = hat + (size_t)bid * (IN_CAPS * DIM_CAPS);

  uint4 g[8];
#pragma unroll
  for (int q = 0; q < 8; ++q)
    g[q] = *reinterpret_cast<const uint4*>(base + (size_t)(t + 512 * q) * 8);

  // H(q,s): fp16 value of hat[i_q][8*mh + s]
#define HVAL(q, s) __half2float(__ushort_as_half((ushort_t)( \
    ((s) & 1) ? (((const unsigned int*)&g[(q)])[(s) >> 1] >> 16) \
              : (((const unsigned int*)&g[(q)])[(s) >> 1] & 0xffffu))))

  const int b1 = (lane >> 1) & 1;
  const int b2 = (lane >> 2) & 1;
  const int b3 = (lane >> 3) & 1;
  // final m index this lane's butterfly result represents
  const int m_fin = 8 * mh + 4 * b3 + 2 * b2 + b1;

  float lg[8];
#pragma unroll
  for (int q = 0; q < 8; ++q) lg[q] = 0.f;

  for (int r = 0; r < NROUTE; ++r) {
    float e[8];
    float Ep = 0.f;
    if (r == 0) {
#pragma unroll
      for (int q = 0; q < 8; ++q) e[q] = 1.f;
    } else {
#pragma unroll
      for (int q = 0; q < 8; ++q) { e[q] = __expf(lg[q]); Ep += e[q]; }
    }

    // acc[s] = sum over my 8 i's of e_i * hat[i][8*mh+s]
    float acc[8];
#pragma unroll
    for (int s = 0; s < 8; ++s) {
      float a = 0.f;
#pragma unroll
      for (int q = 0; q < 8; ++q) a = fmaf(e[q], HVAL(q, s), a);
      acc[s] = a;
    }

    // ---- split-butterfly reduction over the wave (m-half already on bit0)
    float v4[4];
#pragma unroll
    for (int k = 0; k < 4; ++k) {               // xor 2  <-> s bit0
      float send = b1 ? acc[2 * k] : acc[2 * k + 1];
      float recv = __shfl_xor(send, 2);
      float keep = b1 ? acc[2 * k + 1] : acc[2 * k];
      v4[k] = keep + recv;                      // s = 2k + b1
    }
    float v2[2];
#pragma unroll
    for (int k = 0; k < 2; ++k) {               // xor 4  <-> s bit1
      float send = b2 ? v4[2 * k] : v4[2 * k + 1];
      float recv = __shfl_xor(send, 4);
      float keep = b2 ? v4[2 * k + 1] : v4[2 * k];
      v2[k] = keep + recv;                      // s = 4k + 2*b2 + b1
    }
    float z;
    {                                           // xor 8  <-> s bit2
      float send = b3 ? v2[0] : v2[1];
      float recv = __shfl_xor(send, 8);
      float keep = b3 ? v2[1] : v2[0];
      z = keep + recv;                          // s = 4*b3 + 2*b2 + b1
    }
    z += __shfl_xor(z, 16);
    z += __shfl_xor(z, 32);                     // summed over whole wave

    if (r > 0) {                                // E over wave: bits 1..5 only
      Ep += __shfl_xor(Ep, 2);
      Ep += __shfl_xor(Ep, 4);
      Ep += __shfl_xor(Ep, 8);
      Ep += __shfl_xor(Ep, 16);
      Ep += __shfl_xor(Ep, 32);
      if (lane == 16) red[wv][16] = Ep;
    }
    if (lane < 16) red[wv][m_fin] = z;
    __syncthreads();

    if (t < 16) {
      float s = 0.f;
#pragma unroll
      for (int w = 0; w < 8; ++w) s += red[w][t];
      float E;
      if (r == 0) E = (float)IN_CAPS;
      else {
        E = 0.f;
#pragma unroll
        for (int w = 0; w < 8; ++w) E += red[w][16];
      }
      float sm = s / E;
      float n2 = sm * sm;
#pragma unroll
      for (int off = 8; off >= 1; off >>= 1) n2 += __shfl_xor(n2, off);
      const float scale = n2 / (1.0f + n2) * rsqrtf(n2 + CAPS_EPS);
      const float o = scale * sm;
      outs[t] = o;
      if (r == NROUTE - 1)
        out[(size_t)bid * DIM_CAPS + t] = o;
    }
    __syncthreads();

    if (r < NROUTE - 1) {
      // logit update: lg_i += sum_m outs[m]*hat[i][m]; my half + partner half
#pragma unroll
      for (int q = 0; q < 8; ++q) {
        float d = 0.f;
#pragma unroll
        for (int s = 0; s < 8; ++s) d = fmaf(outs[8 * mh + s], HVAL(q, s), d);
        d += __shfl_xor(d, 1);                  // add partner's m-half
        lg[q] += d;
      }
    }
  }
#undef HVAL
}

extern "C" void kernel_launch(void* const* d_in, const int* in_sizes, int n_in,
                              void* d_out, int out_size, void* d_ws, size_t ws_size,
                              hipStream_t stream) {
  (void)in_sizes; (void)n_in; (void)out_size; (void)ws_size;
  const float* x = (const float*)d_in[0];      // [64][2048][16]
  const float* W = (const float*)d_in[1];      // [2048][32][16][16]
  float* outp = (float*)d_out;                 // [64][32][16]
  ushort_t* hat = (ushort_t*)d_ws;             // [64][32][2048][16] fp16 = 134 MB

  caps_hat_kernel<<<dim3(128, 32), dim3(256), 0, stream>>>(x, W, hat);
  caps_route_kernel<<<dim3(BATCH * NUM_CAPS), dim3(512), 0, stream>>>(hat, outp);
}